// Round 1
// baseline (2635.703 us; speedup 1.0000x reference)
//
#include <hip/hip_runtime.h>
#include <hip/hip_bf16.h>

// ---------- helpers ----------
__device__ inline unsigned fkey(float x) {
    unsigned u = __float_as_uint(x);
    return (u & 0x80000000u) ? ~u : (u | 0x80000000u);
}
__device__ inline float funkey(unsigned k) {
    unsigned u = (k & 0x80000000u) ? (k & 0x7FFFFFFFu) : ~k;
    return __uint_as_float(u);
}
__device__ inline float lrelu(float x) { return x > 0.f ? x : 0.2f * x; }

// ---------- kernels ----------
// O[n,c] = sum_k A[n,k] * B[k,c]
__global__ void gemm_nn(const float* __restrict__ A, const float* __restrict__ B,
                        float* __restrict__ O, int N, int K, int C) {
    long long total = (long long)N * C;
    long long stride = (long long)gridDim.x * blockDim.x;
    for (long long i = (long long)blockIdx.x * blockDim.x + threadIdx.x; i < total; i += stride) {
        int n = (int)(i / C);
        int c = (int)(i % C);
        const float* a = A + (long long)n * K;
        float acc = 0.f;
#pragma unroll 8
        for (int k = 0; k < K; ++k) acc += a[k] * B[(long long)k * C + c];
        O[i] = acc;
    }
}

// el[n,h] = sum_d feat[n,h,d]*al[h,d]; er likewise. One wave per (n,h). D % 64 == 0.
__global__ void attn_proj(const float* __restrict__ feat, const float* __restrict__ al,
                          const float* __restrict__ ar, float* __restrict__ el,
                          float* __restrict__ er, int N, int H, int D) {
    int lane = threadIdx.x & 63;
    int wib = threadIdx.x >> 6;
    int wpb = blockDim.x >> 6;
    long long wavesTotal = (long long)N * H;
    long long wstride = (long long)gridDim.x * wpb;
    for (long long w = (long long)blockIdx.x * wpb + wib; w < wavesTotal; w += wstride) {
        int h = (int)(w % H);
        const float* f = feat + w * D;
        const float* alh = al + (long long)h * D;
        const float* arh = ar + (long long)h * D;
        float sl = 0.f, sr = 0.f;
        for (int d = lane; d < D; d += 64) {
            float fv = f[d];
            sl += fv * alh[d];
            sr += fv * arh[d];
        }
        for (int off = 32; off; off >>= 1) {
            sl += __shfl_down(sl, off);
            sr += __shfl_down(sr, off);
        }
        if (lane == 0) { el[w] = sl; er[w] = sr; }
    }
}

__global__ void edge_max(const int* __restrict__ src, const int* __restrict__ dst,
                         const float* __restrict__ el, const float* __restrict__ er,
                         unsigned* __restrict__ emaxk, long long E, int H) {
    long long total = E * H;
    long long stride = (long long)gridDim.x * blockDim.x;
    for (long long i = (long long)blockIdx.x * blockDim.x + threadIdx.x; i < total; i += stride) {
        long long e = i / H;
        int h = (int)(i % H);
        int s = src[e], d = dst[e];
        float v = lrelu(el[(long long)s * H + h] + er[(long long)d * H + h]);
        atomicMax(&emaxk[(long long)d * H + h], fkey(v));
    }
}

__global__ void edge_den(const int* __restrict__ src, const int* __restrict__ dst,
                         const float* __restrict__ el, const float* __restrict__ er,
                         const unsigned* __restrict__ emaxk, float* __restrict__ den,
                         long long E, int H) {
    long long total = E * H;
    long long stride = (long long)gridDim.x * blockDim.x;
    for (long long i = (long long)blockIdx.x * blockDim.x + threadIdx.x; i < total; i += stride) {
        long long e = i / H;
        int h = (int)(i % H);
        int s = src[e], d = dst[e];
        float v = lrelu(el[(long long)s * H + h] + er[(long long)d * H + h]);
        float m = funkey(emaxk[(long long)d * H + h]);
        atomicAdd(&den[(long long)d * H + h], expf(v - m));
    }
}

// one wave per (edge, head); scatter alpha*feat[src] into rst[dst]
__global__ void edge_scatter(const int* __restrict__ src, const int* __restrict__ dst,
                             const float* __restrict__ el, const float* __restrict__ er,
                             const unsigned* __restrict__ emaxk, const float* __restrict__ den,
                             const float* __restrict__ feat, float* __restrict__ rst,
                             long long E, int H, int D) {
    int lane = threadIdx.x & 63;
    int wib = threadIdx.x >> 6;
    int wpb = blockDim.x >> 6;
    long long total = E * H;
    long long wstride = (long long)gridDim.x * wpb;
    for (long long w = (long long)blockIdx.x * wpb + wib; w < total; w += wstride) {
        long long e = w / H;
        int h = (int)(w % H);
        int s = src[e], d = dst[e];
        float v = lrelu(el[(long long)s * H + h] + er[(long long)d * H + h]);
        float m = funkey(emaxk[(long long)d * H + h]);
        float dn = den[(long long)d * H + h];
        float alpha = expf(v - m) / fmaxf(dn, 1e-9f);
        const float* fs = feat + ((long long)s * H + h) * D;
        float* rd = rst + ((long long)d * H + h) * D;
        for (int dd = lane; dd < D; dd += 64) {
            atomicAdd(&rd[dd], alpha * fs[dd]);
        }
    }
}

// h1[n,d] = sum_h relu(rst[n,h,d] + bias[h,d])
__global__ void combine_heads(const float* __restrict__ rst, const float* __restrict__ bias,
                              float* __restrict__ h1, int N, int H, int D) {
    long long total = (long long)N * D;
    long long stride = (long long)gridDim.x * blockDim.x;
    for (long long i = (long long)blockIdx.x * blockDim.x + threadIdx.x; i < total; i += stride) {
        int n = (int)(i / D);
        int d = (int)(i % D);
        float acc = 0.f;
        for (int h = 0; h < H; ++h) {
            float v = rst[((long long)n * H + h) * D + d] + bias[h * D + d];
            acc += v > 0.f ? v : 0.f;
        }
        h1[i] = acc;
    }
}

// v = relu(rst2[n,d] + b2[d]); atomicMax into gmaxk[gid[n]*D + d]
__global__ void finalize_node(const float* __restrict__ rst2, const float* __restrict__ b2,
                              const int* __restrict__ gid, unsigned* __restrict__ gmaxk,
                              int N, int D) {
    long long total = (long long)N * D;
    long long stride = (long long)gridDim.x * blockDim.x;
    for (long long i = (long long)blockIdx.x * blockDim.x + threadIdx.x; i < total; i += stride) {
        int n = (int)(i / D);
        int d = (int)(i % D);
        float v = rst2[i] + b2[d];
        v = v > 0.f ? v : 0.f;
        atomicMax(&gmaxk[(long long)gid[n] * D + d], fkey(v));
    }
}

// single block: decode graph maxes, 2-layer MLP, out[32]
__global__ void mlp_head(const unsigned* __restrict__ gkl, const unsigned* __restrict__ gkr,
                         const float* __restrict__ W1, const float* __restrict__ b1,
                         const float* __restrict__ W2, const float* __restrict__ b2,
                         float* __restrict__ out) {
    __shared__ float hcat[32][256];
    __shared__ float h[32][128];
    int t = threadIdx.x;  // 256 threads
    for (int i = t; i < 32 * 128; i += 256) {
        int r = i / 128, c = i % 128;
        unsigned kl = gkl[i];
        unsigned kr = gkr[i];
        hcat[r][c] = (kl == 0u) ? 0.f : funkey(kl);
        hcat[r][128 + c] = (kr == 0u) ? 0.f : funkey(kr);
    }
    __syncthreads();
    for (int i = t; i < 32 * 128; i += 256) {
        int r = i / 128, c = i % 128;
        float acc = b1[c];
        for (int k = 0; k < 256; ++k) acc += hcat[r][k] * W1[k * 128 + c];
        h[r][c] = acc > 0.f ? acc : 0.f;
    }
    __syncthreads();
    if (t < 32) {
        float acc = b2[0];
        for (int k = 0; k < 128; ++k) acc += h[t][k] * W2[k];
        out[t] = acc > 0.f ? acc : 0.f;
    }
}

// ---------- launch ----------
static inline unsigned nblk_elem(long long total) {
    long long b = (total + 255) / 256;
    if (b > 65535) b = 65535;
    if (b < 1) b = 1;
    return (unsigned)b;
}
static inline unsigned nblk_wave(long long waves) {
    long long b = (waves + 3) / 4;  // 4 waves per 256-thread block
    if (b > 65535) b = 65535;
    if (b < 1) b = 1;
    return (unsigned)b;
}

extern "C" void kernel_launch(void* const* d_in, const int* in_sizes, int n_in,
                              void* d_out, int out_size, void* d_ws, size_t ws_size,
                              hipStream_t stream) {
    const float* lig_x = (const float*)d_in[0];
    const int* lig_src = (const int*)d_in[1];
    const int* lig_dst = (const int*)d_in[2];
    const int* lig_gid = (const int*)d_in[3];
    const float* rec_x = (const float*)d_in[4];
    const int* rec_src = (const int*)d_in[5];
    const int* rec_dst = (const int*)d_in[6];
    const int* rec_gid = (const int*)d_in[7];
    const float* W1l = (const float*)d_in[8];
    const float* al1l = (const float*)d_in[9];
    const float* ar1l = (const float*)d_in[10];
    const float* b1l = (const float*)d_in[11];
    const float* W2l = (const float*)d_in[12];
    const float* al2l = (const float*)d_in[13];
    const float* ar2l = (const float*)d_in[14];
    const float* b2l = (const float*)d_in[15];
    const float* W1r = (const float*)d_in[16];
    const float* al1r = (const float*)d_in[17];
    const float* ar1r = (const float*)d_in[18];
    const float* b1r = (const float*)d_in[19];
    const float* W2r = (const float*)d_in[20];
    const float* al2r = (const float*)d_in[21];
    const float* ar2r = (const float*)d_in[22];
    const float* b2r = (const float*)d_in[23];
    const float* Wlin1 = (const float*)d_in[24];
    const float* blin1 = (const float*)d_in[25];
    const float* Wlin2 = (const float*)d_in[26];
    const float* blin2 = (const float*)d_in[27];

    int Nl = in_sizes[0] / 64, El = in_sizes[1];
    int Nr = in_sizes[4] / 64, Er = in_sizes[5];
    long long Nmax = Nl > Nr ? Nl : Nr;

    // workspace layout (aliased):
    char* ws = (char*)d_ws;
    float* featA = (float*)ws;            ws += Nmax * 640 * 4;  // layer1 feat; later h1 + feat2
    float* rstB = (float*)ws;             ws += Nmax * 640 * 4;  // layer1 rst; later rst2
    float* elb = (float*)ws;              ws += Nmax * 10 * 4;
    float* erb = (float*)ws;              ws += Nmax * 10 * 4;
    unsigned* emaxk = (unsigned*)ws;      ws += Nmax * 10 * 4;
    float* den = (float*)ws;              ws += Nmax * 10 * 4;
    unsigned* gkl = (unsigned*)ws;        ws += 32 * 128 * 4;
    unsigned* gkr = (unsigned*)ws;        ws += 32 * 128 * 4;
    float* h1 = featA;                 // [N,64]
    float* feat2 = featA + Nmax * 64;  // [N,128]
    float* rst2 = rstB;                // [N,128]

    hipMemsetAsync(gkl, 0, 32 * 128 * 4, stream);
    hipMemsetAsync(gkr, 0, 32 * 128 * 4, stream);

    auto run_branch = [&](const float* x, const int* src, const int* dst, const int* gid,
                          const float* W1, const float* al1, const float* ar1, const float* b1,
                          const float* W2, const float* al2, const float* ar2, const float* b2,
                          unsigned* gk, int N, int E) {
        long long EL = E;
        // ---- layer 1: H=10, D=64 ----
        hipMemsetAsync(rstB, 0, (size_t)N * 640 * 4, stream);
        hipMemsetAsync(emaxk, 0, (size_t)N * 10 * 4, stream);
        hipMemsetAsync(den, 0, (size_t)N * 10 * 4, stream);
        gemm_nn<<<nblk_elem((long long)N * 640), 256, 0, stream>>>(x, W1, featA, N, 64, 640);
        attn_proj<<<nblk_wave((long long)N * 10), 256, 0, stream>>>(featA, al1, ar1, elb, erb, N, 10, 64);
        edge_max<<<nblk_elem(EL * 10), 256, 0, stream>>>(src, dst, elb, erb, emaxk, EL, 10);
        edge_den<<<nblk_elem(EL * 10), 256, 0, stream>>>(src, dst, elb, erb, emaxk, den, EL, 10);
        edge_scatter<<<nblk_wave(EL * 10), 256, 0, stream>>>(src, dst, elb, erb, emaxk, den,
                                                             featA, rstB, EL, 10, 64);
        combine_heads<<<nblk_elem((long long)N * 64), 256, 0, stream>>>(rstB, b1, h1, N, 10, 64);
        // ---- layer 2: H=1, D=128 ----
        gemm_nn<<<nblk_elem((long long)N * 128), 256, 0, stream>>>(h1, W2, feat2, N, 64, 128);
        hipMemsetAsync(rst2, 0, (size_t)N * 128 * 4, stream);
        hipMemsetAsync(emaxk, 0, (size_t)N * 4, stream);
        hipMemsetAsync(den, 0, (size_t)N * 4, stream);
        attn_proj<<<nblk_wave((long long)N), 256, 0, stream>>>(feat2, al2, ar2, elb, erb, N, 1, 128);
        edge_max<<<nblk_elem(EL), 256, 0, stream>>>(src, dst, elb, erb, emaxk, EL, 1);
        edge_den<<<nblk_elem(EL), 256, 0, stream>>>(src, dst, elb, erb, emaxk, den, EL, 1);
        edge_scatter<<<nblk_wave(EL), 256, 0, stream>>>(src, dst, elb, erb, emaxk, den,
                                                        feat2, rst2, EL, 1, 128);
        finalize_node<<<nblk_elem((long long)N * 128), 256, 0, stream>>>(rst2, b2, gid, gk, N, 128);
    };

    run_branch(lig_x, lig_src, lig_dst, lig_gid, W1l, al1l, ar1l, b1l, W2l, al2l, ar2l, b2l,
               gkl, Nl, El);
    run_branch(rec_x, rec_src, rec_dst, rec_gid, W1r, al1r, ar1r, b1r, W2r, al2r, ar2r, b2r,
               gkr, Nr, Er);

    mlp_head<<<1, 256, 0, stream>>>(gkl, gkr, Wlin1, blin1, Wlin2, blin2, (float*)d_out);
}

// Round 2
// 1306.140 us; speedup vs baseline: 2.0179x; 2.0179x over previous
//
#include <hip/hip_runtime.h>
#include <hip/hip_bf16.h>

// ---------- helpers ----------
__device__ inline unsigned fkey(float x) {
    unsigned u = __float_as_uint(x);
    return (u & 0x80000000u) ? ~u : (u | 0x80000000u);
}
__device__ inline float funkey(unsigned k) {
    unsigned u = (k & 0x80000000u) ? (k & 0x7FFFFFFFu) : ~k;
    return __uint_as_float(u);
}
__device__ inline float lrelu(float x) { return x > 0.f ? x : 0.2f * x; }

// ---------- GEMM: O[n,c] = sum_k A[n,k]*B[k,c], 4 outputs per thread ----------
__global__ void gemm_nn4(const float* __restrict__ A, const float* __restrict__ B,
                         float* __restrict__ O, int N, int K, int C) {
    int C4 = C >> 2;
    long long total = (long long)N * C4;
    long long stride = (long long)gridDim.x * blockDim.x;
    for (long long i = (long long)blockIdx.x * blockDim.x + threadIdx.x; i < total; i += stride) {
        int n = (int)(i / C4);
        int c = (int)(i % C4) << 2;
        const float* a = A + (long long)n * K;
        float4 acc = make_float4(0.f, 0.f, 0.f, 0.f);
#pragma unroll 4
        for (int k = 0; k < K; ++k) {
            float av = a[k];
            float4 b = *reinterpret_cast<const float4*>(&B[(long long)k * C + c]);
            acc.x += av * b.x; acc.y += av * b.y; acc.z += av * b.z; acc.w += av * b.w;
        }
        *reinterpret_cast<float4*>(&O[(long long)n * C + c]) = acc;
    }
}

// ---------- el/er projections: one wave per (n,h) ----------
__global__ void attn_proj(const float* __restrict__ feat, const float* __restrict__ al,
                          const float* __restrict__ ar, float* __restrict__ el,
                          float* __restrict__ er, int N, int H, int D) {
    int lane = threadIdx.x & 63;
    int wib = threadIdx.x >> 6;
    int wpb = blockDim.x >> 6;
    long long wavesTotal = (long long)N * H;
    long long wstride = (long long)gridDim.x * wpb;
    for (long long w = (long long)blockIdx.x * wpb + wib; w < wavesTotal; w += wstride) {
        int h = (int)(w % H);
        const float* f = feat + w * D;
        const float* alh = al + (long long)h * D;
        const float* arh = ar + (long long)h * D;
        float sl = 0.f, sr = 0.f;
        for (int d = lane; d < D; d += 64) {
            float fv = f[d];
            sl += fv * alh[d];
            sr += fv * arh[d];
        }
        for (int off = 32; off; off >>= 1) {
            sl += __shfl_down(sl, off);
            sr += __shfl_down(sr, off);
        }
        if (lane == 0) { el[w] = sl; er[w] = sr; }
    }
}

// ---------- CSR build ----------
__global__ void count_deg(const int* __restrict__ dst, int* __restrict__ deg, int E) {
    int stride = gridDim.x * blockDim.x;
    for (int i = blockIdx.x * blockDim.x + threadIdx.x; i < E; i += stride)
        atomicAdd(&deg[dst[i]], 1);
}

// single block, 1024 threads: exclusive scan deg[0..N) -> rowptr[0..N]
__global__ void build_rowptr(const int* __restrict__ deg, int* __restrict__ rowptr, int N) {
    __shared__ int ssum[1024];
    int t = threadIdx.x;
    int nt = blockDim.x;
    int chunk = (N + nt - 1) / nt;
    int beg = t * chunk;
    int end = beg + chunk; if (end > N) end = N; if (beg > N) beg = N;
    int s = 0;
    for (int i = beg; i < end; ++i) s += deg[i];
    ssum[t] = s;
    __syncthreads();
    for (int off = 1; off < nt; off <<= 1) {
        int v = (t >= off) ? ssum[t - off] : 0;
        __syncthreads();
        ssum[t] += v;
        __syncthreads();
    }
    int run = (t == 0) ? 0 : ssum[t - 1];
    for (int i = beg; i < end; ++i) { rowptr[i] = run; run += deg[i]; }
    if (t == nt - 1) rowptr[N] = run;
}

__global__ void fill_adj(const int* __restrict__ src, const int* __restrict__ dst,
                         int* __restrict__ cursor, int* __restrict__ adj, int E) {
    int stride = gridDim.x * blockDim.x;
    for (int i = blockIdx.x * blockDim.x + threadIdx.x; i < E; i += stride) {
        int pos = atomicAdd(&cursor[dst[i]], 1);
        adj[pos] = src[i];
    }
}

// ---------- fused GAT aggregation: one wave per dst node ----------
// H heads, D = DV*64 dims. Computes per-head softmax over in-edges and the
// weighted sum of feat[src], all in registers. Epilogue:
//   gid == nullptr : out[n, d] = sum_h relu(rst[h,d] + bias[h*D+d])   (layer 1)
//   gid != nullptr : atomicMax(gk[gid[n]*D + d], fkey(relu(rst+bias)))  (layer 2)
template <int H, int DV>
__global__ void gat_gather(const int* __restrict__ rowptr, const int* __restrict__ adj,
                           const float* __restrict__ el, const float* __restrict__ er,
                           const float* __restrict__ feat, const float* __restrict__ bias,
                           float* __restrict__ out, const int* __restrict__ gid,
                           unsigned* __restrict__ gk, int N) {
    const int D = DV * 64;
    int lane = threadIdx.x & 63;
    int wib = threadIdx.x >> 6;
    int wpb = blockDim.x >> 6;
    int wstride = gridDim.x * wpb;
    for (int n = blockIdx.x * wpb + wib; n < N; n += wstride) {
        int rbeg = rowptr[n], rend = rowptr[n + 1];
        float erh[H], m[H];
#pragma unroll
        for (int h = 0; h < H; ++h) {
            erh[h] = er[(long long)n * H + h];
            m[h] = -INFINITY;
        }
        // pass 1: per-head max
        for (int j = rbeg; j < rend; ++j) {
            int s = __builtin_amdgcn_readfirstlane(adj[j]);
            const float* els = el + (long long)s * H;
#pragma unroll
            for (int h = 0; h < H; ++h)
                m[h] = fmaxf(m[h], lrelu(els[h] + erh[h]));
        }
        // pass 2: denom + weighted accumulation
        float den[H], acc[H][DV];
#pragma unroll
        for (int h = 0; h < H; ++h) {
            den[h] = 0.f;
#pragma unroll
            for (int v = 0; v < DV; ++v) acc[h][v] = 0.f;
        }
        for (int j = rbeg; j < rend; ++j) {
            int s = __builtin_amdgcn_readfirstlane(adj[j]);
            const float* els = el + (long long)s * H;
            const float* fs = feat + (long long)s * H * D;
#pragma unroll
            for (int h = 0; h < H; ++h) {
                float ex = expf(lrelu(els[h] + erh[h]) - m[h]);
                den[h] += ex;
#pragma unroll
                for (int v = 0; v < DV; ++v)
                    acc[h][v] += ex * fs[h * D + v * 64 + lane];
            }
        }
        // epilogue
        if (gid == nullptr) {
            float o[DV];
#pragma unroll
            for (int v = 0; v < DV; ++v) o[v] = 0.f;
#pragma unroll
            for (int h = 0; h < H; ++h) {
                float inv = 1.f / fmaxf(den[h], 1e-9f);
#pragma unroll
                for (int v = 0; v < DV; ++v) {
                    float val = acc[h][v] * inv + bias[h * D + v * 64 + lane];
                    o[v] += val > 0.f ? val : 0.f;
                }
            }
#pragma unroll
            for (int v = 0; v < DV; ++v)
                out[(long long)n * D + v * 64 + lane] = o[v];
        } else {
            int g = gid[n];
#pragma unroll
            for (int h = 0; h < H; ++h) {
                float inv = 1.f / fmaxf(den[h], 1e-9f);
#pragma unroll
                for (int v = 0; v < DV; ++v) {
                    float val = acc[h][v] * inv + bias[h * D + v * 64 + lane];
                    val = val > 0.f ? val : 0.f;
                    atomicMax(&gk[(long long)g * D + v * 64 + lane], fkey(val));
                }
            }
        }
    }
}

// ---------- head MLP ----------
__global__ void mlp_head(const unsigned* __restrict__ gkl, const unsigned* __restrict__ gkr,
                         const float* __restrict__ W1, const float* __restrict__ b1,
                         const float* __restrict__ W2, const float* __restrict__ b2,
                         float* __restrict__ out) {
    __shared__ float hcat[32][256];
    __shared__ float h[32][128];
    int t = threadIdx.x;  // 256 threads
    for (int i = t; i < 32 * 128; i += 256) {
        int r = i / 128, c = i % 128;
        unsigned kl = gkl[i];
        unsigned kr = gkr[i];
        hcat[r][c] = (kl == 0u) ? 0.f : funkey(kl);
        hcat[r][128 + c] = (kr == 0u) ? 0.f : funkey(kr);
    }
    __syncthreads();
    for (int i = t; i < 32 * 128; i += 256) {
        int r = i / 128, c = i % 128;
        float acc = b1[c];
        for (int k = 0; k < 256; ++k) acc += hcat[r][k] * W1[k * 128 + c];
        h[r][c] = acc > 0.f ? acc : 0.f;
    }
    __syncthreads();
    if (t < 32) {
        float acc = b2[0];
        for (int k = 0; k < 128; ++k) acc += h[t][k] * W2[k];
        out[t] = acc > 0.f ? acc : 0.f;
    }
}

// ---------- launch ----------
static inline unsigned nblk_elem(long long total) {
    long long b = (total + 255) / 256;
    if (b > 65535) b = 65535;
    if (b < 1) b = 1;
    return (unsigned)b;
}
static inline unsigned nblk_wave(long long waves) {
    long long b = (waves + 3) / 4;
    if (b > 65535) b = 65535;
    if (b < 1) b = 1;
    return (unsigned)b;
}

extern "C" void kernel_launch(void* const* d_in, const int* in_sizes, int n_in,
                              void* d_out, int out_size, void* d_ws, size_t ws_size,
                              hipStream_t stream) {
    const float* lig_x = (const float*)d_in[0];
    const int* lig_src = (const int*)d_in[1];
    const int* lig_dst = (const int*)d_in[2];
    const int* lig_gid = (const int*)d_in[3];
    const float* rec_x = (const float*)d_in[4];
    const int* rec_src = (const int*)d_in[5];
    const int* rec_dst = (const int*)d_in[6];
    const int* rec_gid = (const int*)d_in[7];
    const float* W1l = (const float*)d_in[8];
    const float* al1l = (const float*)d_in[9];
    const float* ar1l = (const float*)d_in[10];
    const float* b1l = (const float*)d_in[11];
    const float* W2l = (const float*)d_in[12];
    const float* al2l = (const float*)d_in[13];
    const float* ar2l = (const float*)d_in[14];
    const float* b2l = (const float*)d_in[15];
    const float* W1r = (const float*)d_in[16];
    const float* al1r = (const float*)d_in[17];
    const float* ar1r = (const float*)d_in[18];
    const float* b1r = (const float*)d_in[19];
    const float* W2r = (const float*)d_in[20];
    const float* al2r = (const float*)d_in[21];
    const float* ar2r = (const float*)d_in[22];
    const float* b2r = (const float*)d_in[23];
    const float* Wlin1 = (const float*)d_in[24];
    const float* blin1 = (const float*)d_in[25];
    const float* Wlin2 = (const float*)d_in[26];
    const float* blin2 = (const float*)d_in[27];

    int Nl = in_sizes[0] / 64, El = in_sizes[1];
    int Nr = in_sizes[4] / 64, Er = in_sizes[5];
    long long Nmax = Nl > Nr ? Nl : Nr;
    long long Emax = El > Er ? El : Er;

    // workspace layout
    char* ws = (char*)d_ws;
    float* feat = (float*)ws;        ws += Nmax * 640 * 4;   // layer1 feat; aliased as feat2 later
    float* h1 = (float*)ws;          ws += Nmax * 64 * 4;
    float* elb = (float*)ws;         ws += Nmax * 10 * 4;
    float* erb = (float*)ws;         ws += Nmax * 10 * 4;
    int* deg = (int*)ws;             ws += Nmax * 4;
    int* cursor = (int*)ws;          ws += Nmax * 4;
    int* rowptr = (int*)ws;          ws += (Nmax + 1) * 4;
    int* adj = (int*)ws;             ws += Emax * 4;
    unsigned* gkl = (unsigned*)ws;   ws += 32 * 128 * 4;
    unsigned* gkr = (unsigned*)ws;   ws += 32 * 128 * 4;
    float* feat2 = feat;  // [N,128], safe: written after feat no longer needed

    hipMemsetAsync(gkl, 0, 32 * 128 * 4, stream);
    hipMemsetAsync(gkr, 0, 32 * 128 * 4, stream);

    auto run_branch = [&](const float* x, const int* src, const int* dst, const int* gid,
                          const float* W1, const float* al1, const float* ar1, const float* b1,
                          const float* W2, const float* al2, const float* ar2, const float* b2,
                          unsigned* gk, int N, int E) {
        // CSR (shared by both layers)
        hipMemsetAsync(deg, 0, (size_t)N * 4, stream);
        count_deg<<<nblk_elem(E), 256, 0, stream>>>(dst, deg, E);
        build_rowptr<<<1, 1024, 0, stream>>>(deg, rowptr, N);
        hipMemcpyAsync(cursor, rowptr, (size_t)N * 4, hipMemcpyDeviceToDevice, stream);
        fill_adj<<<nblk_elem(E), 256, 0, stream>>>(src, dst, cursor, adj, E);

        // ---- layer 1: H=10, D=64 ----
        gemm_nn4<<<nblk_elem((long long)N * 160), 256, 0, stream>>>(x, W1, feat, N, 64, 640);
        attn_proj<<<nblk_wave((long long)N * 10), 256, 0, stream>>>(feat, al1, ar1, elb, erb, N, 10, 64);
        gat_gather<10, 1><<<nblk_wave(N), 256, 0, stream>>>(rowptr, adj, elb, erb, feat, b1,
                                                            h1, nullptr, nullptr, N);
        // ---- layer 2: H=1, D=128 ----
        gemm_nn4<<<nblk_elem((long long)N * 32), 256, 0, stream>>>(h1, W2, feat2, N, 64, 128);
        attn_proj<<<nblk_wave((long long)N), 256, 0, stream>>>(feat2, al2, ar2, elb, erb, N, 1, 128);
        gat_gather<1, 2><<<nblk_wave(N), 256, 0, stream>>>(rowptr, adj, elb, erb, feat2, b2,
                                                           nullptr, gid, gk, N);
    };

    run_branch(lig_x, lig_src, lig_dst, lig_gid, W1l, al1l, ar1l, b1l, W2l, al2l, ar2l, b2l,
               gkl, Nl, El);
    run_branch(rec_x, rec_src, rec_dst, rec_gid, W1r, al1r, ar1r, b1r, W2r, al2r, ar2r, b2r,
               gkr, Nr, Er);

    mlp_head<<<1, 256, 0, stream>>>(gkl, gkr, Wlin1, blin1, Wlin2, blin2, (float*)d_out);
}

// Round 3
// 1228.484 us; speedup vs baseline: 2.1455x; 1.0632x over previous
//
#include <hip/hip_runtime.h>
#include <hip/hip_bf16.h>

// ---------- helpers ----------
__device__ inline unsigned fkey(float x) {
    unsigned u = __float_as_uint(x);
    return (u & 0x80000000u) ? ~u : (u | 0x80000000u);
}
__device__ inline float funkey(unsigned k) {
    unsigned u = (k & 0x80000000u) ? (k & 0x7FFFFFFFu) : ~k;
    return __uint_as_float(u);
}
__device__ inline float lrelu(float x) { return x > 0.f ? x : 0.2f * x; }

// ---------- LDS-tiled GEMM, K=64 fixed: O[n,c] = sum_k A[n,k]*B[k,c] ----------
// grid = (ceil(N/64), C/64), block = 256. Each thread computes 4 rows x 4 cols.
__global__ __launch_bounds__(256) void gemm_tiled(const float* __restrict__ A,
                                                  const float* __restrict__ B,
                                                  float* __restrict__ O, int N, int C) {
    __shared__ __align__(16) float As[64][68];  // +4 pad: b128-aligned, 2-way max conflicts
    __shared__ __align__(16) float Bs[64][64];
    int row0 = blockIdx.x * 64;
    int col0 = blockIdx.y * 64;
    int t = threadIdx.x;

    // stage A tile: A rows are exactly 64 floats -> tile is 4096 contiguous floats
    const float* Abase = A + (size_t)row0 * 64;
    int maxElems = (N - row0) * 64;  // valid floats in this tile
#pragma unroll
    for (int p = 0; p < 4; ++p) {
        int idx = t + p * 256;           // float4 index, 0..1023
        int r = idx >> 4, k0 = (idx & 15) << 2;
        float4 v = make_float4(0.f, 0.f, 0.f, 0.f);
        if (idx * 4 < maxElems) v = *reinterpret_cast<const float4*>(Abase + (size_t)idx * 4);
        As[r][k0] = v.x; As[r][k0 + 1] = v.y; As[r][k0 + 2] = v.z; As[r][k0 + 3] = v.w;
    }
    // stage B tile: 64 rows of C-stride
#pragma unroll
    for (int p = 0; p < 4; ++p) {
        int idx = t + p * 256;
        int k = idx >> 4, c0 = (idx & 15) << 2;
        float4 v = *reinterpret_cast<const float4*>(B + (size_t)k * C + col0 + c0);
        *reinterpret_cast<float4*>(&Bs[k][c0]) = v;
    }
    __syncthreads();

    int c0 = (t & 15) * 4;
    int r0 = (t >> 4) * 4;
    float4 acc[4];
#pragma unroll
    for (int i = 0; i < 4; ++i) acc[i] = make_float4(0.f, 0.f, 0.f, 0.f);

    for (int k0 = 0; k0 < 64; k0 += 4) {
        float4 a[4], b[4];
#pragma unroll
        for (int i = 0; i < 4; ++i) a[i] = *reinterpret_cast<const float4*>(&As[r0 + i][k0]);
#pragma unroll
        for (int j = 0; j < 4; ++j) b[j] = *reinterpret_cast<const float4*>(&Bs[k0 + j][c0]);
#pragma unroll
        for (int i = 0; i < 4; ++i) {
            acc[i].x += a[i].x * b[0].x + a[i].y * b[1].x + a[i].z * b[2].x + a[i].w * b[3].x;
            acc[i].y += a[i].x * b[0].y + a[i].y * b[1].y + a[i].z * b[2].y + a[i].w * b[3].y;
            acc[i].z += a[i].x * b[0].z + a[i].y * b[1].z + a[i].z * b[2].z + a[i].w * b[3].z;
            acc[i].w += a[i].x * b[0].w + a[i].y * b[1].w + a[i].z * b[2].w + a[i].w * b[3].w;
        }
    }

#pragma unroll
    for (int i = 0; i < 4; ++i) {
        int row = row0 + r0 + i;
        if (row < N)
            *reinterpret_cast<float4*>(&O[(size_t)row * C + col0 + c0]) = acc[i];
    }
}

// ---------- fold attention vectors through W: Walr[k][h]=sum_d W[k,h*D+d]*al[h,d] ----------
// one wave per k (k < 64). Walr layout: [64][2H], first H = left, last H = right.
__global__ void fold_attn(const float* __restrict__ W, const float* __restrict__ al,
                          const float* __restrict__ ar, float* __restrict__ Walr,
                          int H, int D) {
    int k = blockIdx.x;
    int lane = threadIdx.x;
    int C = H * D;
    for (int h = 0; h < H; ++h) {
        float sl = 0.f, sr = 0.f;
        for (int d = lane; d < D; d += 64) {
            float w = W[(size_t)k * C + h * D + d];
            sl += w * al[h * D + d];
            sr += w * ar[h * D + d];
        }
        for (int off = 32; off; off >>= 1) {
            sl += __shfl_down(sl, off);
            sr += __shfl_down(sr, off);
        }
        if (lane == 0) {
            Walr[k * 2 * H + h] = sl;
            Walr[k * 2 * H + H + h] = sr;
        }
    }
}

// ---------- el/er from 64-dim input: one wave per node ----------
__global__ void attn_from_x(const float* __restrict__ in, const float* __restrict__ Walr,
                            float* __restrict__ el, float* __restrict__ er, int N, int H) {
    int lane = threadIdx.x & 63;
    int wib = threadIdx.x >> 6;
    int wpb = blockDim.x >> 6;
    int wstride = gridDim.x * wpb;
    int H2 = 2 * H;
    for (int n = blockIdx.x * wpb + wib; n < N; n += wstride) {
        float x = in[(size_t)n * 64 + lane];
        const float* wrow = Walr + lane * H2;
        for (int h = 0; h < H2; ++h) {
            float s = x * wrow[h];
            for (int off = 32; off; off >>= 1) s += __shfl_down(s, off);
            if (lane == 0) {
                if (h < H) el[(size_t)n * H + h] = s;
                else       er[(size_t)n * H + h - H] = s;
            }
        }
    }
}

// ---------- CSR build ----------
__global__ void count_deg(const int* __restrict__ dst, int* __restrict__ deg, int E) {
    int stride = gridDim.x * blockDim.x;
    for (int i = blockIdx.x * blockDim.x + threadIdx.x; i < E; i += stride)
        atomicAdd(&deg[dst[i]], 1);
}

__global__ void build_rowptr(const int* __restrict__ deg, int* __restrict__ rowptr, int N) {
    __shared__ int ssum[1024];
    int t = threadIdx.x;
    int nt = blockDim.x;
    int chunk = (N + nt - 1) / nt;
    int beg = t * chunk;
    int end = beg + chunk; if (end > N) end = N; if (beg > N) beg = N;
    int s = 0;
    for (int i = beg; i < end; ++i) s += deg[i];
    ssum[t] = s;
    __syncthreads();
    for (int off = 1; off < nt; off <<= 1) {
        int v = (t >= off) ? ssum[t - off] : 0;
        __syncthreads();
        ssum[t] += v;
        __syncthreads();
    }
    int run = (t == 0) ? 0 : ssum[t - 1];
    for (int i = beg; i < end; ++i) { rowptr[i] = run; run += deg[i]; }
    if (t == nt - 1) rowptr[N] = run;
}

__global__ void fill_adj(const int* __restrict__ src, const int* __restrict__ dst,
                         int* __restrict__ cursor, int* __restrict__ adj, int E) {
    int stride = gridDim.x * blockDim.x;
    for (int i = blockIdx.x * blockDim.x + threadIdx.x; i < E; i += stride) {
        int pos = atomicAdd(&cursor[dst[i]], 1);
        adj[pos] = src[i];
    }
}

// ---------- fused GAT aggregation: one wave per dst node ----------
template <int H, int DV>
__global__ void gat_gather(const int* __restrict__ rowptr, const int* __restrict__ adj,
                           const float* __restrict__ el, const float* __restrict__ er,
                           const float* __restrict__ feat, const float* __restrict__ bias,
                           float* __restrict__ out, const int* __restrict__ gid,
                           unsigned* __restrict__ gk, int N) {
    const int D = DV * 64;
    int lane = threadIdx.x & 63;
    int wib = threadIdx.x >> 6;
    int wpb = blockDim.x >> 6;
    int wstride = gridDim.x * wpb;
    for (int n = blockIdx.x * wpb + wib; n < N; n += wstride) {
        int rbeg = rowptr[n], rend = rowptr[n + 1];
        float erh[H], m[H];
#pragma unroll
        for (int h = 0; h < H; ++h) {
            erh[h] = er[(long long)n * H + h];
            m[h] = -INFINITY;
        }
        for (int j = rbeg; j < rend; ++j) {
            int s = __builtin_amdgcn_readfirstlane(adj[j]);
            const float* els = el + (long long)s * H;
#pragma unroll
            for (int h = 0; h < H; ++h)
                m[h] = fmaxf(m[h], lrelu(els[h] + erh[h]));
        }
        float den[H], acc[H][DV];
#pragma unroll
        for (int h = 0; h < H; ++h) {
            den[h] = 0.f;
#pragma unroll
            for (int v = 0; v < DV; ++v) acc[h][v] = 0.f;
        }
        for (int j = rbeg; j < rend; ++j) {
            int s = __builtin_amdgcn_readfirstlane(adj[j]);
            const float* els = el + (long long)s * H;
            const float* fs = feat + (long long)s * H * D;
#pragma unroll
            for (int h = 0; h < H; ++h) {
                float ex = expf(lrelu(els[h] + erh[h]) - m[h]);
                den[h] += ex;
#pragma unroll
                for (int v = 0; v < DV; ++v)
                    acc[h][v] += ex * fs[h * D + v * 64 + lane];
            }
        }
        if (gid == nullptr) {
            float o[DV];
#pragma unroll
            for (int v = 0; v < DV; ++v) o[v] = 0.f;
#pragma unroll
            for (int h = 0; h < H; ++h) {
                float inv = 1.f / fmaxf(den[h], 1e-9f);
#pragma unroll
                for (int v = 0; v < DV; ++v) {
                    float val = acc[h][v] * inv + bias[h * D + v * 64 + lane];
                    o[v] += val > 0.f ? val : 0.f;
                }
            }
#pragma unroll
            for (int v = 0; v < DV; ++v)
                out[(long long)n * D + v * 64 + lane] = o[v];
        } else {
            int g = gid[n];
#pragma unroll
            for (int h = 0; h < H; ++h) {
                float inv = 1.f / fmaxf(den[h], 1e-9f);
#pragma unroll
                for (int v = 0; v < DV; ++v) {
                    float val = acc[h][v] * inv + bias[h * D + v * 64 + lane];
                    val = val > 0.f ? val : 0.f;
                    atomicMax(&gk[(long long)g * D + v * 64 + lane], fkey(val));
                }
            }
        }
    }
}

// ---------- head MLP ----------
__global__ void mlp_head(const unsigned* __restrict__ gkl, const unsigned* __restrict__ gkr,
                         const float* __restrict__ W1, const float* __restrict__ b1,
                         const float* __restrict__ W2, const float* __restrict__ b2,
                         float* __restrict__ out) {
    __shared__ float hcat[32][256];
    __shared__ float h[32][128];
    int t = threadIdx.x;  // 256 threads
    for (int i = t; i < 32 * 128; i += 256) {
        int r = i / 128, c = i % 128;
        unsigned kl = gkl[i];
        unsigned kr = gkr[i];
        hcat[r][c] = (kl == 0u) ? 0.f : funkey(kl);
        hcat[r][128 + c] = (kr == 0u) ? 0.f : funkey(kr);
    }
    __syncthreads();
    for (int i = t; i < 32 * 128; i += 256) {
        int r = i / 128, c = i % 128;
        float acc = b1[c];
        for (int k = 0; k < 256; ++k) acc += hcat[r][k] * W1[k * 128 + c];
        h[r][c] = acc > 0.f ? acc : 0.f;
    }
    __syncthreads();
    if (t < 32) {
        float acc = b2[0];
        for (int k = 0; k < 128; ++k) acc += h[t][k] * W2[k];
        out[t] = acc > 0.f ? acc : 0.f;
    }
}

// ---------- launch ----------
static inline unsigned nblk_elem(long long total) {
    long long b = (total + 255) / 256;
    if (b > 65535) b = 65535;
    if (b < 1) b = 1;
    return (unsigned)b;
}
static inline unsigned nblk_wave(long long waves) {
    long long b = (waves + 3) / 4;
    if (b > 65535) b = 65535;
    if (b < 1) b = 1;
    return (unsigned)b;
}

extern "C" void kernel_launch(void* const* d_in, const int* in_sizes, int n_in,
                              void* d_out, int out_size, void* d_ws, size_t ws_size,
                              hipStream_t stream) {
    const float* lig_x = (const float*)d_in[0];
    const int* lig_src = (const int*)d_in[1];
    const int* lig_dst = (const int*)d_in[2];
    const int* lig_gid = (const int*)d_in[3];
    const float* rec_x = (const float*)d_in[4];
    const int* rec_src = (const int*)d_in[5];
    const int* rec_dst = (const int*)d_in[6];
    const int* rec_gid = (const int*)d_in[7];
    const float* W1l = (const float*)d_in[8];
    const float* al1l = (const float*)d_in[9];
    const float* ar1l = (const float*)d_in[10];
    const float* b1l = (const float*)d_in[11];
    const float* W2l = (const float*)d_in[12];
    const float* al2l = (const float*)d_in[13];
    const float* ar2l = (const float*)d_in[14];
    const float* b2l = (const float*)d_in[15];
    const float* W1r = (const float*)d_in[16];
    const float* al1r = (const float*)d_in[17];
    const float* ar1r = (const float*)d_in[18];
    const float* b1r = (const float*)d_in[19];
    const float* W2r = (const float*)d_in[20];
    const float* al2r = (const float*)d_in[21];
    const float* ar2r = (const float*)d_in[22];
    const float* b2r = (const float*)d_in[23];
    const float* Wlin1 = (const float*)d_in[24];
    const float* blin1 = (const float*)d_in[25];
    const float* Wlin2 = (const float*)d_in[26];
    const float* blin2 = (const float*)d_in[27];

    int Nl = in_sizes[0] / 64, El = in_sizes[1];
    int Nr = in_sizes[4] / 64, Er = in_sizes[5];
    long long Nmax = Nl > Nr ? Nl : Nr;
    long long Emax = El > Er ? El : Er;

    // workspace layout
    char* ws = (char*)d_ws;
    float* feat = (float*)ws;        ws += Nmax * 640 * 4;   // layer1 feat; aliased as feat2
    float* h1 = (float*)ws;          ws += Nmax * 64 * 4;
    float* elb = (float*)ws;         ws += Nmax * 10 * 4;
    float* erb = (float*)ws;         ws += Nmax * 10 * 4;
    int* deg = (int*)ws;             ws += Nmax * 4;
    int* cursor = (int*)ws;          ws += Nmax * 4;
    int* rowptr = (int*)ws;          ws += (Nmax + 1) * 4;
    int* adj = (int*)ws;             ws += Emax * 4;
    unsigned* gkl = (unsigned*)ws;   ws += 32 * 128 * 4;
    unsigned* gkr = (unsigned*)ws;   ws += 32 * 128 * 4;
    float* Walr = (float*)ws;        ws += 64 * 32 * 4;
    float* feat2 = feat;  // [N,128]

    hipMemsetAsync(gkl, 0, 32 * 128 * 4, stream);
    hipMemsetAsync(gkr, 0, 32 * 128 * 4, stream);

    auto run_branch = [&](const float* x, const int* src, const int* dst, const int* gid,
                          const float* W1, const float* al1, const float* ar1, const float* b1,
                          const float* W2, const float* al2, const float* ar2, const float* b2,
                          unsigned* gk, int N, int E) {
        // CSR (shared by both layers)
        hipMemsetAsync(deg, 0, (size_t)N * 4, stream);
        count_deg<<<nblk_elem(E), 256, 0, stream>>>(dst, deg, E);
        build_rowptr<<<1, 1024, 0, stream>>>(deg, rowptr, N);
        hipMemcpyAsync(cursor, rowptr, (size_t)N * 4, hipMemcpyDeviceToDevice, stream);
        fill_adj<<<nblk_elem(E), 256, 0, stream>>>(src, dst, cursor, adj, E);

        // ---- layer 1: H=10, D=64 ----
        gemm_tiled<<<dim3((N + 63) / 64, 10), 256, 0, stream>>>(x, W1, feat, N, 640);
        fold_attn<<<64, 64, 0, stream>>>(W1, al1, ar1, Walr, 10, 64);
        attn_from_x<<<nblk_wave(N), 256, 0, stream>>>(x, Walr, elb, erb, N, 10);
        gat_gather<10, 1><<<nblk_wave(N), 256, 0, stream>>>(rowptr, adj, elb, erb, feat, b1,
                                                            h1, nullptr, nullptr, N);
        // ---- layer 2: H=1, D=128 ----
        gemm_tiled<<<dim3((N + 63) / 64, 2), 256, 0, stream>>>(h1, W2, feat2, N, 128);
        fold_attn<<<64, 64, 0, stream>>>(W2, al2, ar2, Walr, 1, 128);
        attn_from_x<<<nblk_wave(N), 256, 0, stream>>>(h1, Walr, elb, erb, N, 1);
        gat_gather<1, 2><<<nblk_wave(N), 256, 0, stream>>>(rowptr, adj, elb, erb, feat2, b2,
                                                           nullptr, gid, gk, N);
    };

    run_branch(lig_x, lig_src, lig_dst, lig_gid, W1l, al1l, ar1l, b1l, W2l, al2l, ar2l, b2l,
               gkl, Nl, El);
    run_branch(rec_x, rec_src, rec_dst, rec_gid, W1r, al1r, ar1r, b1r, W2r, al2r, ar2r, b2r,
               gkr, Nr, Er);

    mlp_head<<<1, 256, 0, stream>>>(gkl, gkr, Wlin1, blin1, Wlin2, blin2, (float*)d_out);
}

// Round 4
// 1067.524 us; speedup vs baseline: 2.4690x; 1.1508x over previous
//
#include <hip/hip_runtime.h>
#include <hip/hip_bf16.h>

// ---------- helpers ----------
__device__ inline unsigned fkey(float x) {
    unsigned u = __float_as_uint(x);
    return (u & 0x80000000u) ? ~u : (u | 0x80000000u);
}
__device__ inline float funkey(unsigned k) {
    unsigned u = (k & 0x80000000u) ? (k & 0x7FFFFFFFu) : ~k;
    return __uint_as_float(u);
}
__device__ inline float lrelu(float x) { return x > 0.f ? x : 0.2f * x; }

// ---------- LDS-tiled GEMM, K=64 fixed: O[n,c] = sum_k A[n,k]*B[k,c] ----------
__global__ __launch_bounds__(256) void gemm_tiled(const float* __restrict__ A,
                                                  const float* __restrict__ B,
                                                  float* __restrict__ O, int N, int C) {
    __shared__ __align__(16) float As[64][68];
    __shared__ __align__(16) float Bs[64][64];
    int row0 = blockIdx.x * 64;
    int col0 = blockIdx.y * 64;
    int t = threadIdx.x;

    const float* Abase = A + (size_t)row0 * 64;
    int maxElems = (N - row0) * 64;
#pragma unroll
    for (int p = 0; p < 4; ++p) {
        int idx = t + p * 256;
        int r = idx >> 4, k0 = (idx & 15) << 2;
        float4 v = make_float4(0.f, 0.f, 0.f, 0.f);
        if (idx * 4 < maxElems) v = *reinterpret_cast<const float4*>(Abase + (size_t)idx * 4);
        As[r][k0] = v.x; As[r][k0 + 1] = v.y; As[r][k0 + 2] = v.z; As[r][k0 + 3] = v.w;
    }
#pragma unroll
    for (int p = 0; p < 4; ++p) {
        int idx = t + p * 256;
        int k = idx >> 4, c0 = (idx & 15) << 2;
        float4 v = *reinterpret_cast<const float4*>(B + (size_t)k * C + col0 + c0);
        *reinterpret_cast<float4*>(&Bs[k][c0]) = v;
    }
    __syncthreads();

    int c0 = (t & 15) * 4;
    int r0 = (t >> 4) * 4;
    float4 acc[4];
#pragma unroll
    for (int i = 0; i < 4; ++i) acc[i] = make_float4(0.f, 0.f, 0.f, 0.f);

    for (int k0 = 0; k0 < 64; k0 += 4) {
        float4 a[4], b[4];
#pragma unroll
        for (int i = 0; i < 4; ++i) a[i] = *reinterpret_cast<const float4*>(&As[r0 + i][k0]);
#pragma unroll
        for (int j = 0; j < 4; ++j) b[j] = *reinterpret_cast<const float4*>(&Bs[k0 + j][c0]);
#pragma unroll
        for (int i = 0; i < 4; ++i) {
            acc[i].x += a[i].x * b[0].x + a[i].y * b[1].x + a[i].z * b[2].x + a[i].w * b[3].x;
            acc[i].y += a[i].x * b[0].y + a[i].y * b[1].y + a[i].z * b[2].y + a[i].w * b[3].y;
            acc[i].z += a[i].x * b[0].z + a[i].y * b[1].z + a[i].z * b[2].z + a[i].w * b[3].z;
            acc[i].w += a[i].x * b[0].w + a[i].y * b[1].w + a[i].z * b[2].w + a[i].w * b[3].w;
        }
    }

#pragma unroll
    for (int i = 0; i < 4; ++i) {
        int row = row0 + r0 + i;
        if (row < N)
            *reinterpret_cast<float4*>(&O[(size_t)row * C + col0 + c0]) = acc[i];
    }
}

// ---------- fold attention vectors through W ----------
__global__ void fold_attn(const float* __restrict__ W, const float* __restrict__ al,
                          const float* __restrict__ ar, float* __restrict__ Walr,
                          int H, int D) {
    int k = blockIdx.x;
    int lane = threadIdx.x;
    int C = H * D;
    for (int h = 0; h < H; ++h) {
        float sl = 0.f, sr = 0.f;
        for (int d = lane; d < D; d += 64) {
            float w = W[(size_t)k * C + h * D + d];
            sl += w * al[h * D + d];
            sr += w * ar[h * D + d];
        }
        for (int off = 32; off; off >>= 1) {
            sl += __shfl_down(sl, off);
            sr += __shfl_down(sr, off);
        }
        if (lane == 0) {
            Walr[k * 2 * H + h] = sl;
            Walr[k * 2 * H + H + h] = sr;
        }
    }
}

// ---------- el/er from 64-dim input: one wave per node ----------
__global__ void attn_from_x(const float* __restrict__ in, const float* __restrict__ Walr,
                            float* __restrict__ el, float* __restrict__ er, int N, int H) {
    int lane = threadIdx.x & 63;
    int wib = threadIdx.x >> 6;
    int wpb = blockDim.x >> 6;
    int wstride = gridDim.x * wpb;
    int H2 = 2 * H;
    for (int n = blockIdx.x * wpb + wib; n < N; n += wstride) {
        float x = in[(size_t)n * 64 + lane];
        const float* wrow = Walr + lane * H2;
        for (int h = 0; h < H2; ++h) {
            float s = x * wrow[h];
            for (int off = 32; off; off >>= 1) s += __shfl_down(s, off);
            if (lane == 0) {
                if (h < H) el[(size_t)n * H + h] = s;
                else       er[(size_t)n * H + h - H] = s;
            }
        }
    }
}

// ---------- CSR build ----------
__global__ void count_deg(const int* __restrict__ dst, int* __restrict__ deg, int E) {
    int stride = gridDim.x * blockDim.x;
    for (int i = blockIdx.x * blockDim.x + threadIdx.x; i < E; i += stride)
        atomicAdd(&deg[dst[i]], 1);
}

__global__ void build_rowptr(const int* __restrict__ deg, int* __restrict__ rowptr, int N) {
    __shared__ int ssum[1024];
    int t = threadIdx.x;
    int nt = blockDim.x;
    int chunk = (N + nt - 1) / nt;
    int beg = t * chunk;
    int end = beg + chunk; if (end > N) end = N; if (beg > N) beg = N;
    int s = 0;
    for (int i = beg; i < end; ++i) s += deg[i];
    ssum[t] = s;
    __syncthreads();
    for (int off = 1; off < nt; off <<= 1) {
        int v = (t >= off) ? ssum[t - off] : 0;
        __syncthreads();
        ssum[t] += v;
        __syncthreads();
    }
    int run = (t == 0) ? 0 : ssum[t - 1];
    for (int i = beg; i < end; ++i) { rowptr[i] = run; run += deg[i]; }
    if (t == nt - 1) rowptr[N] = run;
}

__global__ void fill_adj(const int* __restrict__ src, const int* __restrict__ dst,
                         int* __restrict__ cursor, int* __restrict__ adj, int E) {
    int stride = gridDim.x * blockDim.x;
    for (int i = blockIdx.x * blockDim.x + threadIdx.x; i < E; i += stride) {
        int pos = atomicAdd(&cursor[dst[i]], 1);
        adj[pos] = src[i];
    }
}

// ---------- fused GAT aggregation v2: wave per node, two-phase ----------
// Phase A: lane-parallel over (<=64-edge chunk): compute e per edge for all H heads,
//          butterfly-reduce max & denom, stash exp-weights + src ids in LDS.
// Phase B: serial over chunk edges, lane-parallel over D: acc += alpha * feat[src].
template <int H, int DV>
__global__ __launch_bounds__(256) void gat_gather2(
        const int* __restrict__ rowptr, const int* __restrict__ adj,
        const float* __restrict__ el, const float* __restrict__ er,
        const float* __restrict__ feat, const float* __restrict__ bias,
        float* __restrict__ out, const int* __restrict__ gid,
        unsigned* __restrict__ gk, int N) {
    const int D = DV * 64;
    __shared__ float exl[4][H][64];
    __shared__ int sarr[4][64];
    int lane = threadIdx.x & 63;
    int w = threadIdx.x >> 6;
    for (int n = blockIdx.x * 4 + w; n < N; n += gridDim.x * 4) {
        int rbeg = rowptr[n], rend = rowptr[n + 1];
        float erh[H], mrun[H], den[H], acc[H][DV];
#pragma unroll
        for (int h = 0; h < H; ++h) {
            erh[h] = er[(size_t)n * H + h];
            mrun[h] = -INFINITY;
            den[h] = 0.f;
#pragma unroll
            for (int v = 0; v < DV; ++v) acc[h][v] = 0.f;
        }
        for (int base = rbeg; base < rend; base += 64) {
            int cnt = rend - base; if (cnt > 64) cnt = 64;
            int s = (lane < cnt) ? adj[base + lane] : 0;
            // per-lane e for all heads
            float e[H];
#pragma unroll
            for (int h = 0; h < H; ++h)
                e[h] = (lane < cnt) ? lrelu(el[(size_t)s * H + h] + erh[h]) : -INFINITY;
            // chunk max -> new running max, rescale old state
#pragma unroll
            for (int h = 0; h < H; ++h) {
                float cm = e[h];
                for (int off = 32; off; off >>= 1) cm = fmaxf(cm, __shfl_xor(cm, off));
                float newm = fmaxf(mrun[h], cm);
                float scl = __expf(mrun[h] - newm);  // first chunk: exp(-inf)=0
                den[h] *= scl;
#pragma unroll
                for (int v = 0; v < DV; ++v) acc[h][v] *= scl;
                mrun[h] = newm;
            }
            // exp weights, denom reduce, stash to LDS
#pragma unroll
            for (int h = 0; h < H; ++h) {
                float ex = (lane < cnt) ? __expf(e[h] - mrun[h]) : 0.f;
                float sm = ex;
                for (int off = 32; off; off >>= 1) sm += __shfl_xor(sm, off);
                den[h] += sm;
                exl[w][h][lane] = ex;
            }
            sarr[w][lane] = s;
            // Phase B: serial edges, lane-parallel feature accumulate
            for (int jj = 0; jj < cnt; ++jj) {
                int s2 = __builtin_amdgcn_readfirstlane(sarr[w][jj]);
                const float* fs = feat + (size_t)s2 * (H * D);
#pragma unroll
                for (int h = 0; h < H; ++h) {
                    float a = exl[w][h][jj];
#pragma unroll
                    for (int v = 0; v < DV; ++v)
                        acc[h][v] += a * fs[h * D + v * 64 + lane];
                }
            }
        }
        // epilogue
        if (gid == nullptr) {
            float o[DV];
#pragma unroll
            for (int v = 0; v < DV; ++v) o[v] = 0.f;
#pragma unroll
            for (int h = 0; h < H; ++h) {
                float inv = 1.f / fmaxf(den[h], 1e-9f);
#pragma unroll
                for (int v = 0; v < DV; ++v) {
                    float val = acc[h][v] * inv + bias[h * D + v * 64 + lane];
                    o[v] += val > 0.f ? val : 0.f;
                }
            }
#pragma unroll
            for (int v = 0; v < DV; ++v)
                out[(size_t)n * D + v * 64 + lane] = o[v];
        } else {
            int g = gid[n];
#pragma unroll
            for (int h = 0; h < H; ++h) {
                float inv = 1.f / fmaxf(den[h], 1e-9f);
#pragma unroll
                for (int v = 0; v < DV; ++v) {
                    float val = acc[h][v] * inv + bias[h * D + v * 64 + lane];
                    val = val > 0.f ? val : 0.f;
                    atomicMax(&gk[(size_t)g * D + v * 64 + lane], fkey(val));
                }
            }
        }
    }
}

// ---------- head MLP ----------
__global__ void mlp_head(const unsigned* __restrict__ gkl, const unsigned* __restrict__ gkr,
                         const float* __restrict__ W1, const float* __restrict__ b1,
                         const float* __restrict__ W2, const float* __restrict__ b2,
                         float* __restrict__ out) {
    __shared__ float hcat[32][256];
    __shared__ float h[32][128];
    int t = threadIdx.x;  // 256 threads
    for (int i = t; i < 32 * 128; i += 256) {
        int r = i / 128, c = i % 128;
        unsigned kl = gkl[i];
        unsigned kr = gkr[i];
        hcat[r][c] = (kl == 0u) ? 0.f : funkey(kl);
        hcat[r][128 + c] = (kr == 0u) ? 0.f : funkey(kr);
    }
    __syncthreads();
    for (int i = t; i < 32 * 128; i += 256) {
        int r = i / 128, c = i % 128;
        float acc = b1[c];
        for (int k = 0; k < 256; ++k) acc += hcat[r][k] * W1[k * 128 + c];
        h[r][c] = acc > 0.f ? acc : 0.f;
    }
    __syncthreads();
    if (t < 32) {
        float acc = b2[0];
        for (int k = 0; k < 128; ++k) acc += h[t][k] * W2[k];
        out[t] = acc > 0.f ? acc : 0.f;
    }
}

// ---------- launch ----------
static inline unsigned nblk_elem(long long total) {
    long long b = (total + 255) / 256;
    if (b > 65535) b = 65535;
    if (b < 1) b = 1;
    return (unsigned)b;
}
static inline unsigned nblk_gather(long long nodes) {
    long long b = (nodes + 3) / 4;
    if (b > 2048) b = 2048;  // grid-stride: ~8192 waves, several nodes each
    if (b < 1) b = 1;
    return (unsigned)b;
}

extern "C" void kernel_launch(void* const* d_in, const int* in_sizes, int n_in,
                              void* d_out, int out_size, void* d_ws, size_t ws_size,
                              hipStream_t stream) {
    const float* lig_x = (const float*)d_in[0];
    const int* lig_src = (const int*)d_in[1];
    const int* lig_dst = (const int*)d_in[2];
    const int* lig_gid = (const int*)d_in[3];
    const float* rec_x = (const float*)d_in[4];
    const int* rec_src = (const int*)d_in[5];
    const int* rec_dst = (const int*)d_in[6];
    const int* rec_gid = (const int*)d_in[7];
    const float* W1l = (const float*)d_in[8];
    const float* al1l = (const float*)d_in[9];
    const float* ar1l = (const float*)d_in[10];
    const float* b1l = (const float*)d_in[11];
    const float* W2l = (const float*)d_in[12];
    const float* al2l = (const float*)d_in[13];
    const float* ar2l = (const float*)d_in[14];
    const float* b2l = (const float*)d_in[15];
    const float* W1r = (const float*)d_in[16];
    const float* al1r = (const float*)d_in[17];
    const float* ar1r = (const float*)d_in[18];
    const float* b1r = (const float*)d_in[19];
    const float* W2r = (const float*)d_in[20];
    const float* al2r = (const float*)d_in[21];
    const float* ar2r = (const float*)d_in[22];
    const float* b2r = (const float*)d_in[23];
    const float* Wlin1 = (const float*)d_in[24];
    const float* blin1 = (const float*)d_in[25];
    const float* Wlin2 = (const float*)d_in[26];
    const float* blin2 = (const float*)d_in[27];

    int Nl = in_sizes[0] / 64, El = in_sizes[1];
    int Nr = in_sizes[4] / 64, Er = in_sizes[5];
    long long Nmax = Nl > Nr ? Nl : Nr;
    long long Emax = El > Er ? El : Er;

    // workspace layout
    char* ws = (char*)d_ws;
    float* feat = (float*)ws;        ws += Nmax * 640 * 4;   // layer1 feat; aliased as feat2
    float* h1 = (float*)ws;          ws += Nmax * 64 * 4;
    float* elb = (float*)ws;         ws += Nmax * 10 * 4;
    float* erb = (float*)ws;         ws += Nmax * 10 * 4;
    int* deg = (int*)ws;             ws += Nmax * 4;
    int* cursor = (int*)ws;          ws += Nmax * 4;
    int* rowptr = (int*)ws;          ws += (Nmax + 1) * 4;
    int* adj = (int*)ws;             ws += Emax * 4;
    unsigned* gkl = (unsigned*)ws;   ws += 32 * 128 * 4;
    unsigned* gkr = (unsigned*)ws;   ws += 32 * 128 * 4;
    float* Walr = (float*)ws;        ws += 64 * 32 * 4;
    float* feat2 = feat;  // [N,128]

    hipMemsetAsync(gkl, 0, 32 * 128 * 4, stream);
    hipMemsetAsync(gkr, 0, 32 * 128 * 4, stream);

    auto run_branch = [&](const float* x, const int* src, const int* dst, const int* gid,
                          const float* W1, const float* al1, const float* ar1, const float* b1,
                          const float* W2, const float* al2, const float* ar2, const float* b2,
                          unsigned* gk, int N, int E) {
        // CSR (shared by both layers)
        hipMemsetAsync(deg, 0, (size_t)N * 4, stream);
        count_deg<<<nblk_elem(E), 256, 0, stream>>>(dst, deg, E);
        build_rowptr<<<1, 1024, 0, stream>>>(deg, rowptr, N);
        hipMemcpyAsync(cursor, rowptr, (size_t)N * 4, hipMemcpyDeviceToDevice, stream);
        fill_adj<<<nblk_elem(E), 256, 0, stream>>>(src, dst, cursor, adj, E);

        // ---- layer 1: H=10, D=64 ----
        gemm_tiled<<<dim3((N + 63) / 64, 10), 256, 0, stream>>>(x, W1, feat, N, 640);
        fold_attn<<<64, 64, 0, stream>>>(W1, al1, ar1, Walr, 10, 64);
        attn_from_x<<<nblk_gather(N), 256, 0, stream>>>(x, Walr, elb, erb, N, 10);
        gat_gather2<10, 1><<<nblk_gather(N), 256, 0, stream>>>(rowptr, adj, elb, erb, feat, b1,
                                                               h1, nullptr, nullptr, N);
        // ---- layer 2: H=1, D=128 ----
        gemm_tiled<<<dim3((N + 63) / 64, 2), 256, 0, stream>>>(h1, W2, feat2, N, 128);
        fold_attn<<<64, 64, 0, stream>>>(W2, al2, ar2, Walr, 1, 128);
        attn_from_x<<<nblk_gather(N), 256, 0, stream>>>(h1, Walr, elb, erb, N, 1);
        gat_gather2<1, 2><<<nblk_gather(N), 256, 0, stream>>>(rowptr, adj, elb, erb, feat2, b2,
                                                              nullptr, gid, gk, N);
    };

    run_branch(lig_x, lig_src, lig_dst, lig_gid, W1l, al1l, ar1l, b1l, W2l, al2l, ar2l, b2l,
               gkl, Nl, El);
    run_branch(rec_x, rec_src, rec_dst, rec_gid, W1r, al1r, ar1r, b1r, W2r, al2r, ar2r, b2r,
               gkr, Nr, Er);

    mlp_head<<<1, 256, 0, stream>>>(gkl, gkr, Wlin1, blin1, Wlin2, blin2, (float*)d_out);
}

// Round 5
// 841.269 us; speedup vs baseline: 3.1330x; 1.2689x over previous
//
#include <hip/hip_runtime.h>
#include <hip/hip_bf16.h>

// ---------- helpers ----------
__device__ inline unsigned fkey(float x) {
    unsigned u = __float_as_uint(x);
    return (u & 0x80000000u) ? ~u : (u | 0x80000000u);
}
__device__ inline float funkey(unsigned k) {
    unsigned u = (k & 0x80000000u) ? (k & 0x7FFFFFFFu) : ~k;
    return __uint_as_float(u);
}
__device__ inline float lrelu(float x) { return x > 0.f ? x : 0.2f * x; }

// ---------- LDS-tiled GEMM, K=64 fixed: O[n,c] = sum_k A[n,k]*B[k,c] ----------
// __launch_bounds__(256,4): cap VGPR at 128 -> 4 waves/SIMD (round-4 fix: compiler
// fully unrolled k-loop, hit 256 VGPR, occupancy 11%, 200us latency-bound).
__global__ __launch_bounds__(256, 4) void gemm_tiled(const float* __restrict__ A,
                                                     const float* __restrict__ B,
                                                     float* __restrict__ O, int N, int C) {
    __shared__ __align__(16) float As[64][68];
    __shared__ __align__(16) float Bs[64][64];
    int row0 = blockIdx.x * 64;
    int col0 = blockIdx.y * 64;
    int t = threadIdx.x;

    const float* Abase = A + (size_t)row0 * 64;
    int maxElems = (N - row0) * 64;
#pragma unroll
    for (int p = 0; p < 4; ++p) {
        int idx = t + p * 256;
        int r = idx >> 4, k0 = (idx & 15) << 2;
        float4 v = make_float4(0.f, 0.f, 0.f, 0.f);
        if (idx * 4 < maxElems) v = *reinterpret_cast<const float4*>(Abase + (size_t)idx * 4);
        As[r][k0] = v.x; As[r][k0 + 1] = v.y; As[r][k0 + 2] = v.z; As[r][k0 + 3] = v.w;
    }
#pragma unroll
    for (int p = 0; p < 4; ++p) {
        int idx = t + p * 256;
        int k = idx >> 4, c0 = (idx & 15) << 2;
        float4 v = *reinterpret_cast<const float4*>(B + (size_t)k * C + col0 + c0);
        *reinterpret_cast<float4*>(&Bs[k][c0]) = v;
    }
    __syncthreads();

    int c0 = (t & 15) * 4;
    int r0 = (t >> 4) * 4;
    float4 acc[4];
#pragma unroll
    for (int i = 0; i < 4; ++i) acc[i] = make_float4(0.f, 0.f, 0.f, 0.f);

#pragma unroll 2
    for (int k0 = 0; k0 < 64; k0 += 4) {
        float4 a[4], b[4];
#pragma unroll
        for (int i = 0; i < 4; ++i) a[i] = *reinterpret_cast<const float4*>(&As[r0 + i][k0]);
#pragma unroll
        for (int j = 0; j < 4; ++j) b[j] = *reinterpret_cast<const float4*>(&Bs[k0 + j][c0]);
#pragma unroll
        for (int i = 0; i < 4; ++i) {
            acc[i].x += a[i].x * b[0].x + a[i].y * b[1].x + a[i].z * b[2].x + a[i].w * b[3].x;
            acc[i].y += a[i].x * b[0].y + a[i].y * b[1].y + a[i].z * b[2].y + a[i].w * b[3].y;
            acc[i].z += a[i].x * b[0].z + a[i].y * b[1].z + a[i].z * b[2].z + a[i].w * b[3].z;
            acc[i].w += a[i].x * b[0].w + a[i].y * b[1].w + a[i].z * b[2].w + a[i].w * b[3].w;
        }
    }

#pragma unroll
    for (int i = 0; i < 4; ++i) {
        int row = row0 + r0 + i;
        if (row < N)
            *reinterpret_cast<float4*>(&O[(size_t)row * C + col0 + c0]) = acc[i];
    }
}

// ---------- fold attention vectors through W ----------
__global__ void fold_attn(const float* __restrict__ W, const float* __restrict__ al,
                          const float* __restrict__ ar, float* __restrict__ Walr,
                          int H, int D) {
    int k = blockIdx.x;
    int lane = threadIdx.x;
    int C = H * D;
    for (int h = 0; h < H; ++h) {
        float sl = 0.f, sr = 0.f;
        for (int d = lane; d < D; d += 64) {
            float w = W[(size_t)k * C + h * D + d];
            sl += w * al[h * D + d];
            sr += w * ar[h * D + d];
        }
        for (int off = 32; off; off >>= 1) {
            sl += __shfl_down(sl, off);
            sr += __shfl_down(sr, off);
        }
        if (lane == 0) {
            Walr[k * 2 * H + h] = sl;
            Walr[k * 2 * H + H + h] = sr;
        }
    }
}

// ---------- el/er from 64-dim input: one wave per node ----------
__global__ void attn_from_x(const float* __restrict__ in, const float* __restrict__ Walr,
                            float* __restrict__ el, float* __restrict__ er, int N, int H) {
    int lane = threadIdx.x & 63;
    int wib = threadIdx.x >> 6;
    int wpb = blockDim.x >> 6;
    int wstride = gridDim.x * wpb;
    int H2 = 2 * H;
    for (int n = blockIdx.x * wpb + wib; n < N; n += wstride) {
        float x = in[(size_t)n * 64 + lane];
        const float* wrow = Walr + lane * H2;
        for (int h = 0; h < H2; ++h) {
            float s = x * wrow[h];
            for (int off = 32; off; off >>= 1) s += __shfl_down(s, off);
            if (lane == 0) {
                if (h < H) el[(size_t)n * H + h] = s;
                else       er[(size_t)n * H + h - H] = s;
            }
        }
    }
}

// ---------- CSR build ----------
__global__ void count_deg(const int* __restrict__ dst, int* __restrict__ deg, int E) {
    int stride = gridDim.x * blockDim.x;
    for (int i = blockIdx.x * blockDim.x + threadIdx.x; i < E; i += stride)
        atomicAdd(&deg[dst[i]], 1);
}

__global__ void build_rowptr(const int* __restrict__ deg, int* __restrict__ rowptr, int N) {
    __shared__ int ssum[1024];
    int t = threadIdx.x;
    int nt = blockDim.x;
    int chunk = (N + nt - 1) / nt;
    int beg = t * chunk;
    int end = beg + chunk; if (end > N) end = N; if (beg > N) beg = N;
    int s = 0;
    for (int i = beg; i < end; ++i) s += deg[i];
    ssum[t] = s;
    __syncthreads();
    for (int off = 1; off < nt; off <<= 1) {
        int v = (t >= off) ? ssum[t - off] : 0;
        __syncthreads();
        ssum[t] += v;
        __syncthreads();
    }
    int run = (t == 0) ? 0 : ssum[t - 1];
    for (int i = beg; i < end; ++i) { rowptr[i] = run; run += deg[i]; }
    if (t == nt - 1) rowptr[N] = run;
}

__global__ void fill_adj(const int* __restrict__ src, const int* __restrict__ dst,
                         int* __restrict__ cursor, int* __restrict__ adj, int E) {
    int stride = gridDim.x * blockDim.x;
    for (int i = blockIdx.x * blockDim.x + threadIdx.x; i < E; i += stride) {
        int pos = atomicAdd(&cursor[dst[i]], 1);
        adj[pos] = src[i];
    }
}

// ---------- fused GAT aggregation v2: wave per node, two-phase ----------
template <int H, int DV>
__global__ __launch_bounds__(256) void gat_gather2(
        const int* __restrict__ rowptr, const int* __restrict__ adj,
        const float* __restrict__ el, const float* __restrict__ er,
        const float* __restrict__ feat, const float* __restrict__ bias,
        float* __restrict__ out, const int* __restrict__ gid,
        unsigned* __restrict__ gk, int N) {
    const int D = DV * 64;
    __shared__ float exl[4][H][64];
    __shared__ int sarr[4][64];
    int lane = threadIdx.x & 63;
    int w = threadIdx.x >> 6;
    for (int n = blockIdx.x * 4 + w; n < N; n += gridDim.x * 4) {
        int rbeg = rowptr[n], rend = rowptr[n + 1];
        float erh[H], mrun[H], den[H], acc[H][DV];
#pragma unroll
        for (int h = 0; h < H; ++h) {
            erh[h] = er[(size_t)n * H + h];
            mrun[h] = -INFINITY;
            den[h] = 0.f;
#pragma unroll
            for (int v = 0; v < DV; ++v) acc[h][v] = 0.f;
        }
        for (int base = rbeg; base < rend; base += 64) {
            int cnt = rend - base; if (cnt > 64) cnt = 64;
            int s = (lane < cnt) ? adj[base + lane] : 0;
            float e[H];
#pragma unroll
            for (int h = 0; h < H; ++h)
                e[h] = (lane < cnt) ? lrelu(el[(size_t)s * H + h] + erh[h]) : -INFINITY;
#pragma unroll
            for (int h = 0; h < H; ++h) {
                float cm = e[h];
                for (int off = 32; off; off >>= 1) cm = fmaxf(cm, __shfl_xor(cm, off));
                float newm = fmaxf(mrun[h], cm);
                float scl = __expf(mrun[h] - newm);
                den[h] *= scl;
#pragma unroll
                for (int v = 0; v < DV; ++v) acc[h][v] *= scl;
                mrun[h] = newm;
            }
#pragma unroll
            for (int h = 0; h < H; ++h) {
                float ex = (lane < cnt) ? __expf(e[h] - mrun[h]) : 0.f;
                float sm = ex;
                for (int off = 32; off; off >>= 1) sm += __shfl_xor(sm, off);
                den[h] += sm;
                exl[w][h][lane] = ex;
            }
            sarr[w][lane] = s;
            for (int jj = 0; jj < cnt; ++jj) {
                int s2 = __builtin_amdgcn_readfirstlane(sarr[w][jj]);
                const float* fs = feat + (size_t)s2 * (H * D);
#pragma unroll
                for (int h = 0; h < H; ++h) {
                    float a = exl[w][h][jj];
#pragma unroll
                    for (int v = 0; v < DV; ++v)
                        acc[h][v] += a * fs[h * D + v * 64 + lane];
                }
            }
        }
        if (gid == nullptr) {
            float o[DV];
#pragma unroll
            for (int v = 0; v < DV; ++v) o[v] = 0.f;
#pragma unroll
            for (int h = 0; h < H; ++h) {
                float inv = 1.f / fmaxf(den[h], 1e-9f);
#pragma unroll
                for (int v = 0; v < DV; ++v) {
                    float val = acc[h][v] * inv + bias[h * D + v * 64 + lane];
                    o[v] += val > 0.f ? val : 0.f;
                }
            }
#pragma unroll
            for (int v = 0; v < DV; ++v)
                out[(size_t)n * D + v * 64 + lane] = o[v];
        } else {
            int g = gid[n];
#pragma unroll
            for (int h = 0; h < H; ++h) {
                float inv = 1.f / fmaxf(den[h], 1e-9f);
#pragma unroll
                for (int v = 0; v < DV; ++v) {
                    float val = acc[h][v] * inv + bias[h * D + v * 64 + lane];
                    val = val > 0.f ? val : 0.f;
                    atomicMax(&gk[(size_t)g * D + v * 64 + lane], fkey(val));
                }
            }
        }
    }
}

// ---------- head MLP ----------
__global__ void mlp_head(const unsigned* __restrict__ gkl, const unsigned* __restrict__ gkr,
                         const float* __restrict__ W1, const float* __restrict__ b1,
                         const float* __restrict__ W2, const float* __restrict__ b2,
                         float* __restrict__ out) {
    __shared__ float hcat[32][256];
    __shared__ float h[32][128];
    int t = threadIdx.x;  // 256 threads
    for (int i = t; i < 32 * 128; i += 256) {
        int r = i / 128, c = i % 128;
        unsigned kl = gkl[i];
        unsigned kr = gkr[i];
        hcat[r][c] = (kl == 0u) ? 0.f : funkey(kl);
        hcat[r][128 + c] = (kr == 0u) ? 0.f : funkey(kr);
    }
    __syncthreads();
    for (int i = t; i < 32 * 128; i += 256) {
        int r = i / 128, c = i % 128;
        float acc = b1[c];
        for (int k = 0; k < 256; ++k) acc += hcat[r][k] * W1[k * 128 + c];
        h[r][c] = acc > 0.f ? acc : 0.f;
    }
    __syncthreads();
    if (t < 32) {
        float acc = b2[0];
        for (int k = 0; k < 128; ++k) acc += h[t][k] * W2[k];
        out[t] = acc > 0.f ? acc : 0.f;
    }
}

// ---------- launch ----------
static inline unsigned nblk_elem(long long total) {
    long long b = (total + 255) / 256;
    if (b > 65535) b = 65535;
    if (b < 1) b = 1;
    return (unsigned)b;
}
static inline unsigned nblk_gather(long long nodes) {
    long long b = (nodes + 3) / 4;
    if (b > 2048) b = 2048;
    if (b < 1) b = 1;
    return (unsigned)b;
}

extern "C" void kernel_launch(void* const* d_in, const int* in_sizes, int n_in,
                              void* d_out, int out_size, void* d_ws, size_t ws_size,
                              hipStream_t stream) {
    const float* lig_x = (const float*)d_in[0];
    const int* lig_src = (const int*)d_in[1];
    const int* lig_dst = (const int*)d_in[2];
    const int* lig_gid = (const int*)d_in[3];
    const float* rec_x = (const float*)d_in[4];
    const int* rec_src = (const int*)d_in[5];
    const int* rec_dst = (const int*)d_in[6];
    const int* rec_gid = (const int*)d_in[7];
    const float* W1l = (const float*)d_in[8];
    const float* al1l = (const float*)d_in[9];
    const float* ar1l = (const float*)d_in[10];
    const float* b1l = (const float*)d_in[11];
    const float* W2l = (const float*)d_in[12];
    const float* al2l = (const float*)d_in[13];
    const float* ar2l = (const float*)d_in[14];
    const float* b2l = (const float*)d_in[15];
    const float* W1r = (const float*)d_in[16];
    const float* al1r = (const float*)d_in[17];
    const float* ar1r = (const float*)d_in[18];
    const float* b1r = (const float*)d_in[19];
    const float* W2r = (const float*)d_in[20];
    const float* al2r = (const float*)d_in[21];
    const float* ar2r = (const float*)d_in[22];
    const float* b2r = (const float*)d_in[23];
    const float* Wlin1 = (const float*)d_in[24];
    const float* blin1 = (const float*)d_in[25];
    const float* Wlin2 = (const float*)d_in[26];
    const float* blin2 = (const float*)d_in[27];

    int Nl = in_sizes[0] / 64, El = in_sizes[1];
    int Nr = in_sizes[4] / 64, Er = in_sizes[5];
    long long Nmax = Nl > Nr ? Nl : Nr;
    long long Emax = El > Er ? El : Er;

    // workspace layout
    char* ws = (char*)d_ws;
    float* feat = (float*)ws;        ws += Nmax * 640 * 4;   // layer1 feat; aliased as feat2
    float* h1 = (float*)ws;          ws += Nmax * 64 * 4;
    float* elb = (float*)ws;         ws += Nmax * 10 * 4;
    float* erb = (float*)ws;         ws += Nmax * 10 * 4;
    int* deg = (int*)ws;             ws += Nmax * 4;
    int* cursor = (int*)ws;          ws += Nmax * 4;
    int* rowptr = (int*)ws;          ws += (Nmax + 1) * 4;
    int* adj = (int*)ws;             ws += Emax * 4;
    unsigned* gkl = (unsigned*)ws;   ws += 32 * 128 * 4;
    unsigned* gkr = (unsigned*)ws;   ws += 32 * 128 * 4;
    float* Walr = (float*)ws;        ws += 64 * 32 * 4;
    float* feat2 = feat;  // [N,128]

    hipMemsetAsync(gkl, 0, 32 * 128 * 4, stream);
    hipMemsetAsync(gkr, 0, 32 * 128 * 4, stream);

    auto run_branch = [&](const float* x, const int* src, const int* dst, const int* gid,
                          const float* W1, const float* al1, const float* ar1, const float* b1,
                          const float* W2, const float* al2, const float* ar2, const float* b2,
                          unsigned* gk, int N, int E) {
        // CSR (shared by both layers)
        hipMemsetAsync(deg, 0, (size_t)N * 4, stream);
        count_deg<<<nblk_elem(E), 256, 0, stream>>>(dst, deg, E);
        build_rowptr<<<1, 1024, 0, stream>>>(deg, rowptr, N);
        hipMemcpyAsync(cursor, rowptr, (size_t)N * 4, hipMemcpyDeviceToDevice, stream);
        fill_adj<<<nblk_elem(E), 256, 0, stream>>>(src, dst, cursor, adj, E);

        // ---- layer 1: H=10, D=64 ----
        gemm_tiled<<<dim3((N + 63) / 64, 10), 256, 0, stream>>>(x, W1, feat, N, 640);
        fold_attn<<<64, 64, 0, stream>>>(W1, al1, ar1, Walr, 10, 64);
        attn_from_x<<<nblk_gather(N), 256, 0, stream>>>(x, Walr, elb, erb, N, 10);
        gat_gather2<10, 1><<<nblk_gather(N), 256, 0, stream>>>(rowptr, adj, elb, erb, feat, b1,
                                                               h1, nullptr, nullptr, N);
        // ---- layer 2: H=1, D=128 ----
        gemm_tiled<<<dim3((N + 63) / 64, 2), 256, 0, stream>>>(h1, W2, feat2, N, 128);
        fold_attn<<<64, 64, 0, stream>>>(W2, al2, ar2, Walr, 1, 128);
        attn_from_x<<<nblk_gather(N), 256, 0, stream>>>(h1, Walr, elb, erb, N, 1);
        gat_gather2<1, 2><<<nblk_gather(N), 256, 0, stream>>>(rowptr, adj, elb, erb, feat2, b2,
                                                              nullptr, gid, gk, N);
    };

    run_branch(lig_x, lig_src, lig_dst, lig_gid, W1l, al1l, ar1l, b1l, W2l, al2l, ar2l, b2l,
               gkl, Nl, El);
    run_branch(rec_x, rec_src, rec_dst, rec_gid, W1r, al1r, ar1r, b1r, W2r, al2r, ar2r, b2r,
               gkr, Nr, Er);

    mlp_head<<<1, 256, 0, stream>>>(gkl, gkr, Wlin1, blin1, Wlin2, blin2, (float*)d_out);
}